// Round 6
// baseline (612.651 us; speedup 1.0000x reference)
//
#include <hip/hip_runtime.h>
#include <hip/hip_bf16.h>
#include <hip/hip_fp16.h>
#include <math.h>

#define NN 100000
#define EE 1600000
#define HD_ 128   // heads*hid = 4*32
#define NT 16     // nodes per proj block (acc = float2[16] = 32 VGPR -> no spill)

typedef float f32x4 __attribute__((ext_vector_type(4)));

// ---------------------------------------------------------------------------
// fast tanh via hardware exp, overflow-safe form
// ---------------------------------------------------------------------------
__device__ __forceinline__ float fast_tanh(float z) {
    float az = fabsf(z);
    float e = __expf(-2.f * az);
    float t = (1.f - e) / (1.f + e);
    return copysignf(t, z);
}

struct alignas(16) h8 { __half2 h[4]; };  // 8 halves = 16B

__device__ __forceinline__ void nt_store_h2(__half* p, __half2 v) {
    __builtin_nontemporal_store(*reinterpret_cast<unsigned int*>(&v),
                                reinterpret_cast<unsigned int*>(p));
}

// ---------------------------------------------------------------------------
// Kernel 1: fused projections. block = 256 = 4 waves; wave w owns matrix w
// (0:Q, 1:K, 2:V, 3:S). 16 nodes/block. acc = float2[16] (32 VGPR) so the
// accumulator stays in registers (NT=32 spilled: VGPR_Count 60 < 74 needed,
// ~460MB of scratch writes). Outputs fp16:
//   Qh[node][128] (pre-scaled by 1/sqrt(32)), Sh[node][128],
//   KV[node][256] (k: 0..127, v: 128..255).
// ---------------------------------------------------------------------------
__global__ __launch_bounds__(256) void proj_kernel(
    const float* __restrict__ x,
    const float* __restrict__ Wq, const float* __restrict__ bq,
    const float* __restrict__ Wk, const float* __restrict__ bk,
    const float* __restrict__ Wv, const float* __restrict__ bv,
    const float* __restrict__ Ws, const float* __restrict__ bs,
    __half* __restrict__ Qh, __half* __restrict__ Sh, __half* __restrict__ KV)
{
    __shared__ float xs[128][20];   // [k][node], pad 20: b128 reads 16B-aligned
    const int tid = threadIdx.x;
    const int n0 = blockIdx.x * NT;

    // load 16 nodes x 128 k, transpose into LDS (nontemporal: read-once)
    {
        const int node = tid & 15;
        const int k0 = (tid >> 4) * 8;
        const f32x4* xp = reinterpret_cast<const f32x4*>(
            x + (size_t)(n0 + node) * 128 + k0);
#pragma unroll
        for (int j = 0; j < 2; ++j) {
            f32x4 a = __builtin_nontemporal_load(xp + j);
            xs[k0 + j * 4 + 0][node] = a.x;
            xs[k0 + j * 4 + 1][node] = a.y;
            xs[k0 + j * 4 + 2][node] = a.z;
            xs[k0 + j * 4 + 3][node] = a.w;
        }
    }
    __syncthreads();

    const int w = tid >> 6;     // which matrix
    const int lane = tid & 63;
    const int c = lane * 2;     // 2 consecutive cols per lane

    const float* Wm = (w == 0) ? Wq : (w == 1) ? Wk : (w == 2) ? Wv : Ws;
    const float* bm = (w == 0) ? bq : (w == 1) ? bk : (w == 2) ? bv : bs;

    float2 acc[NT];
#pragma unroll
    for (int n = 0; n < NT; ++n) acc[n] = make_float2(0.f, 0.f);

#pragma unroll 4
    for (int k = 0; k < 128; ++k) {
        const float2 wv = *reinterpret_cast<const float2*>(Wm + k * 128 + c);
#pragma unroll
        for (int j = 0; j < 4; ++j) {
            float4 xv = *reinterpret_cast<const float4*>(&xs[k][j * 4]);
            acc[j * 4 + 0].x = fmaf(xv.x, wv.x, acc[j * 4 + 0].x);
            acc[j * 4 + 0].y = fmaf(xv.x, wv.y, acc[j * 4 + 0].y);
            acc[j * 4 + 1].x = fmaf(xv.y, wv.x, acc[j * 4 + 1].x);
            acc[j * 4 + 1].y = fmaf(xv.y, wv.y, acc[j * 4 + 1].y);
            acc[j * 4 + 2].x = fmaf(xv.z, wv.x, acc[j * 4 + 2].x);
            acc[j * 4 + 2].y = fmaf(xv.z, wv.y, acc[j * 4 + 2].y);
            acc[j * 4 + 3].x = fmaf(xv.w, wv.x, acc[j * 4 + 3].x);
            acc[j * 4 + 3].y = fmaf(xv.w, wv.y, acc[j * 4 + 3].y);
        }
    }

    const float2 bb = *reinterpret_cast<const float2*>(bm + c);
    const float scale = 0.17677669529663687f;  // 1/sqrt(32)

    __half* Om;
    float sc;
    if (w == 0)      { Om = Qh;       sc = scale; }
    else if (w == 1) { Om = KV;       sc = 1.f;   }
    else if (w == 2) { Om = KV + 128; sc = 1.f;   }
    else             { Om = Sh;       sc = 1.f;   }
    const size_t stride = (w == 1 || w == 2) ? 256 : 128;

#pragma unroll 4
    for (int n = 0; n < NT; ++n) {
        __half2 o = __floats2half2_rn((acc[n].x + bb.x) * sc,
                                      (acc[n].y + bb.y) * sc);
        nt_store_h2(Om + (size_t)(n0 + n) * stride + c, o);
    }
}

// ---------------------------------------------------------------------------
// Kernel 2: degree histogram over dst
// ---------------------------------------------------------------------------
__global__ __launch_bounds__(256) void deg_kernel(const int* __restrict__ ei,
                                                  int* __restrict__ deg)
{
    int e = blockIdx.x * 256 + threadIdx.x;
    if (e < EE) atomicAdd(&deg[ei[EE + e]], 1);
}

// ---------------------------------------------------------------------------
// Kernels 3a/3b/3c: hierarchical exclusive scan of deg -> offs (+cursor copy)
// ---------------------------------------------------------------------------
#define SC_BLK 1024
#define SC_NB ((NN + SC_BLK - 1) / SC_BLK)   // 98

__global__ __launch_bounds__(256) void scanA_kernel(const int* __restrict__ deg,
                                                    int* __restrict__ offs,
                                                    int* __restrict__ bsum)
{
    __shared__ int wsum[4];
    const int tid = threadIdx.x;
    const int lane = tid & 63;
    const int wid = tid >> 6;
    const int base = blockIdx.x * SC_BLK + tid * 4;

    int v[4];
#pragma unroll
    for (int j = 0; j < 4; ++j) v[j] = (base + j < NN) ? deg[base + j] : 0;
    int s = v[0] + v[1] + v[2] + v[3];

    int inc = s;
#pragma unroll
    for (int off = 1; off < 64; off <<= 1) {
        int t = __shfl_up(inc, off);
        if (lane >= off) inc += t;
    }
    if (lane == 63) wsum[wid] = inc;
    __syncthreads();

    int wbase = 0;
    if (wid > 0) wbase += wsum[0];
    if (wid > 1) wbase += wsum[1];
    if (wid > 2) wbase += wsum[2];

    int excl = wbase + inc - s;
#pragma unroll
    for (int j = 0; j < 4; ++j) {
        if (base + j < NN) offs[base + j] = excl;
        excl += v[j];
    }
    if (tid == 255) bsum[blockIdx.x] = wbase + inc;
}

__global__ __launch_bounds__(128) void scanB_kernel(int* __restrict__ bsum)
{
    __shared__ int w0;
    const int tid = threadIdx.x;
    const int lane = tid & 63;
    int v = (tid < SC_NB) ? bsum[tid] : 0;
    int inc = v;
#pragma unroll
    for (int off = 1; off < 64; off <<= 1) {
        int t = __shfl_up(inc, off);
        if (lane >= off) inc += t;
    }
    if (tid == 63) w0 = inc;
    __syncthreads();
    int excl = inc - v + ((tid >= 64) ? w0 : 0);
    if (tid < SC_NB) bsum[tid] = excl;
}

__global__ __launch_bounds__(256) void scanC_kernel(int* __restrict__ offs,
                                                    const int* __restrict__ bsum,
                                                    int* __restrict__ cursor)
{
    int i = blockIdx.x * 256 + threadIdx.x;
    if (i < NN) {
        int v = offs[i] + bsum[i >> 10];
        offs[i] = v;
        cursor[i] = v;
    }
}

// ---------------------------------------------------------------------------
// Kernel 4: scatter edges into dst-sorted order (store src index)
// ---------------------------------------------------------------------------
__global__ __launch_bounds__(256) void scatter_kernel(const int* __restrict__ ei,
                                                      int* __restrict__ cursor,
                                                      int* __restrict__ ssrc)
{
    int e = blockIdx.x * 256 + threadIdx.x;
    if (e < EE) {
        int dst = ei[EE + e];
        int pos = atomicAdd(&cursor[dst], 1);
        ssrc[pos] = ei[e];
    }
}

// ---------------------------------------------------------------------------
// Kernel 5: per-node attention (no-max softmax: scores bounded |p|<~2) +
// skip + tanh + readout MLP.
// One wave per node. Lane layout: eg = lane>>4 (edge slot 0..3),
// li = lane&15 (row position, dims 8*li..8*li+7; head = li>>2).
// Per iteration the wave processes 4 edges; each lane loads 16B of K and 16B
// of V (1KB coalesced per load instr). Dot-reduce: 2 shfl_xor within quads.
// Cross-slot combine (xor 16,32) once at the end.
// ---------------------------------------------------------------------------
__global__ __launch_bounds__(256) void attn_kernel(
    const __half* __restrict__ Qh, const __half* __restrict__ KV,
    const __half* __restrict__ Sh,
    const int* __restrict__ offs, const int* __restrict__ deg,
    const int* __restrict__ ssrc,
    const float* __restrict__ W1, const float* __restrict__ b1,
    const float* __restrict__ W2, const float* __restrict__ b2,
    const float* __restrict__ W3, const float* __restrict__ b3,
    float* __restrict__ out)
{
    const int wid = threadIdx.x >> 6;
    const int lane = threadIdx.x & 63;
    const int node = blockIdx.x * 4 + wid;
    const int eg = lane >> 4;   // edge slot
    const int li = lane & 15;   // position within row

    __shared__ float hs[4][128];
    __shared__ float h1s[4][24];
    __shared__ float h2s[4][8];

    // q dims 8*li .. 8*li+7 (already scaled by 1/sqrt(32) at projection)
    float qf[8];
    {
        const h8 qq = *reinterpret_cast<const h8*>(Qh + (size_t)node * 128 + li * 8);
#pragma unroll
        for (int j = 0; j < 4; ++j) {
            const float2 f = __half22float2(qq.h[j]);
            qf[2 * j] = f.x;
            qf[2 * j + 1] = f.y;
        }
    }

    float a[8];
#pragma unroll
    for (int j = 0; j < 8; ++j) a[j] = 0.f;
    float l = 0.f;

    const int st = offs[node];
    const int dg = deg[node];

    for (int it = 0; it < dg; it += 4) {
        const int e = it + eg;
        const bool valid = e < dg;
        const int src = ssrc[valid ? (st + e) : st];
        const __half* row = KV + (size_t)src * 256 + li * 8;

        const h8 kk = *reinterpret_cast<const h8*>(row);
        float p = 0.f;
#pragma unroll
        for (int j = 0; j < 4; ++j) {
            const float2 kf = __half22float2(kk.h[j]);
            p = fmaf(qf[2 * j], kf.x, p);
            p = fmaf(qf[2 * j + 1], kf.y, p);
        }
        p += __shfl_xor(p, 1);
        p += __shfl_xor(p, 2);   // now each lane has its head's full score

        float w = valid ? __expf(p) : 0.f;

        const h8 vv = *reinterpret_cast<const h8*>(row + 128);
        l += w;
#pragma unroll
        for (int j = 0; j < 4; ++j) {
            const float2 vf = __half22float2(vv.h[j]);
            a[2 * j]     = fmaf(w, vf.x, a[2 * j]);
            a[2 * j + 1] = fmaf(w, vf.y, a[2 * j + 1]);
        }
    }

    // combine the 4 edge slots
#pragma unroll
    for (int j = 0; j < 8; ++j) {
        a[j] += __shfl_xor(a[j], 16);
        a[j] += __shfl_xor(a[j], 32);
    }
    l += __shfl_xor(l, 16);
    l += __shfl_xor(l, 32);

    const float inv = (l > 0.f) ? 1.f / l : 0.f;

    if (eg == 0) {
        const h8 ss = *reinterpret_cast<const h8*>(Sh + (size_t)node * 128 + li * 8);
#pragma unroll
        for (int j = 0; j < 4; ++j) {
            const float2 sf = __half22float2(ss.h[j]);
            hs[wid][li * 8 + 2 * j]     = fast_tanh(a[2 * j] * inv + sf.x);
            hs[wid][li * 8 + 2 * j + 1] = fast_tanh(a[2 * j + 1] * inv + sf.y);
        }
    }
    __syncthreads();

    if (lane < 24) {
        float t = b1[lane];
#pragma unroll 8
        for (int kk = 0; kk < 128; ++kk) t = fmaf(hs[wid][kk], W1[kk * 24 + lane], t);
        h1s[wid][lane] = t - fast_tanh(t);
    }
    __syncthreads();

    if (lane < 8) {
        float u = b2[lane];
#pragma unroll
        for (int kk = 0; kk < 24; ++kk) u = fmaf(h1s[wid][kk], W2[kk * 8 + lane], u);
        h2s[wid][lane] = u - fast_tanh(u);
    }
    __syncthreads();

    if (lane < 2) {
        float o = b3[lane];
#pragma unroll
        for (int kk = 0; kk < 8; ++kk) o = fmaf(h2s[wid][kk], W3[kk * 2 + lane], o);
        __builtin_nontemporal_store(o, out + (size_t)node * 2 + lane);
    }
}

// ---------------------------------------------------------------------------
extern "C" void kernel_launch(void* const* d_in, const int* in_sizes, int n_in,
                              void* d_out, int out_size, void* d_ws, size_t ws_size,
                              hipStream_t stream)
{
    const float* x  = (const float*)d_in[0];
    const int*   ei = (const int*)d_in[1];
    const float* Wq = (const float*)d_in[2];
    const float* bq = (const float*)d_in[3];
    const float* Wk = (const float*)d_in[4];
    const float* bk = (const float*)d_in[5];
    const float* Wv = (const float*)d_in[6];
    const float* bv = (const float*)d_in[7];
    const float* Ws = (const float*)d_in[8];
    const float* bs = (const float*)d_in[9];
    const float* W1 = (const float*)d_in[10];
    const float* b1 = (const float*)d_in[11];
    const float* W2 = (const float*)d_in[12];
    const float* b2 = (const float*)d_in[13];
    const float* W3 = (const float*)d_in[14];
    const float* b3 = (const float*)d_in[15];
    float* out = (float*)d_out;

    __half* ws = (__half*)d_ws;
    __half* Qh = ws;
    __half* Sh = Qh + (size_t)NN * HD_;
    __half* KV = Sh + (size_t)NN * HD_;
    int* deg    = (int*)(KV + (size_t)NN * 256);
    int* offs   = deg + NN;
    int* cursor = offs + NN;
    int* ssrc   = cursor + NN;
    int* bsum   = ssrc + EE;

    (void)hipMemsetAsync(deg, 0, NN * sizeof(int), stream);

    proj_kernel<<<NN / NT, 256, 0, stream>>>(x, Wq, bq, Wk, bk, Wv, bv, Ws, bs,
                                             Qh, Sh, KV);
    deg_kernel<<<(EE + 255) / 256, 256, 0, stream>>>(ei, deg);
    scanA_kernel<<<SC_NB, 256, 0, stream>>>(deg, offs, bsum);
    scanB_kernel<<<1, 128, 0, stream>>>(bsum);
    scanC_kernel<<<(NN + 255) / 256, 256, 0, stream>>>(offs, bsum, cursor);
    scatter_kernel<<<(EE + 255) / 256, 256, 0, stream>>>(ei, cursor, ssrc);
    attn_kernel<<<NN / 4, 256, 0, stream>>>(Qh, KV, Sh, offs, deg, ssrc,
                                            W1, b1, W2, b2, W3, b3, out);
}

// Round 7
// 455.392 us; speedup vs baseline: 1.3453x; 1.3453x over previous
//
#include <hip/hip_runtime.h>
#include <hip/hip_bf16.h>
#include <hip/hip_fp16.h>
#include <math.h>

#define NN 100000
#define EE 1600000
#define HD_ 128   // heads*hid = 4*32

typedef float f32x4 __attribute__((ext_vector_type(4)));
typedef _Float16 f16x8 __attribute__((ext_vector_type(8)));
typedef float accf4 __attribute__((ext_vector_type(4)));

// ---------------------------------------------------------------------------
// fast tanh via hardware exp, overflow-safe form
// ---------------------------------------------------------------------------
__device__ __forceinline__ float fast_tanh(float z) {
    float az = fabsf(z);
    float e = __expf(-2.f * az);
    float t = (1.f - e) / (1.f + e);
    return copysignf(t, z);
}

struct alignas(16) h8 { __half2 h[4]; };  // 8 halves = 16B
struct alignas(8)  h4 { __half2 a, b; };  // 4 halves = 8B

// ---------------------------------------------------------------------------
// Kernel 0: one-time W transpose/convert into MFMA A-fragment layout (fp16).
// Frag index: (((mat*8 + ct)*4 + kt)*64 + lane)*8 + j
//   element = W_mat[kt*32 + (lane>>4)*8 + j][ct*16 + (lane&15)]
// 8192 threads total; W is 256KB read (one-time), Wt is 128KB.
// ---------------------------------------------------------------------------
__global__ __launch_bounds__(256) void wt_kernel(
    const float* __restrict__ Wq, const float* __restrict__ Wk,
    const float* __restrict__ Wv, const float* __restrict__ Ws,
    __half* __restrict__ Wt)
{
    const int t = blockIdx.x * 256 + threadIdx.x;   // 0..8191
    const int lane = t & 63;
    const int kt = (t >> 6) & 3;
    const int ct = (t >> 8) & 7;
    const int mat = t >> 11;
    const float* Wm = (mat == 0) ? Wq : (mat == 1) ? Wk : (mat == 2) ? Wv : Ws;
    const int col = ct * 16 + (lane & 15);
    const int k0 = kt * 32 + (lane >> 4) * 8;
    h8 hh;
#pragma unroll
    for (int j = 0; j < 4; ++j) {
        hh.h[j] = __floats2half2_rn(Wm[(size_t)(k0 + 2 * j) * 128 + col],
                                    Wm[(size_t)(k0 + 2 * j + 1) * 128 + col]);
    }
    *reinterpret_cast<h8*>(Wt + (size_t)t * 8) = hh;
}

// ---------------------------------------------------------------------------
// Kernel 1: fused projections via MFMA (fp16 in, fp32 acc, fp16 out).
// Block = 256 = 4 waves; wave w owns matrix w (0:Q, 1:K, 2:V, 3:S).
// 16 nodes/block. Transposed-operand MFMA: D = Wt_frag (A, m=out-cols) x
// x_frag (B, n=nodes): lane holds node=lane&15, out-cols ct*16+(lane>>4)*4+r.
// Results staged in LDS ys[16][512], then written out as contiguous fp16 rows:
//   Qh[node][128] (pre-scaled by 1/sqrt(32)), Sh[node][128],
//   KV[node][256] (k: 0..127, v: 128..255).
// ---------------------------------------------------------------------------
__global__ __launch_bounds__(256) void proj_mfma(
    const float* __restrict__ x, const __half* __restrict__ Wt,
    const float* __restrict__ bq, const float* __restrict__ bk,
    const float* __restrict__ bv, const float* __restrict__ bs,
    __half* __restrict__ Qh, __half* __restrict__ Sh, __half* __restrict__ KV)
{
    __shared__ __half xs[16][136];   // x tile fp16, padded stride (2-way only)
    __shared__ __half ys[16][520];   // output staging [node][mat*128+col]
    const int tid = threadIdx.x;
    const int n0 = blockIdx.x * 16;

    // stage x[16][128] -> fp16 LDS
    {
        const int row = tid & 15;
        const int k0 = (tid >> 4) * 8;
        const f32x4* xp = reinterpret_cast<const f32x4*>(
            x + (size_t)(n0 + row) * 128 + k0);
        f32x4 a = __builtin_nontemporal_load(xp);
        f32x4 b = __builtin_nontemporal_load(xp + 1);
        h8 hh;
        hh.h[0] = __floats2half2_rn(a.x, a.y);
        hh.h[1] = __floats2half2_rn(a.z, a.w);
        hh.h[2] = __floats2half2_rn(b.x, b.y);
        hh.h[3] = __floats2half2_rn(b.z, b.w);
        *reinterpret_cast<h8*>(&xs[row][k0]) = hh;
    }
    __syncthreads();

    const int w = tid >> 6;     // matrix
    const int lane = tid & 63;
    const float* bm = (w == 0) ? bq : (w == 1) ? bk : (w == 2) ? bv : bs;
    const float sc = (w == 0) ? 0.17677669529663687f : 1.f;  // 1/sqrt(32)

    // x B-fragments (node = lane&15, k = kt*32 + (lane>>4)*8 + j)
    f16x8 bx[4];
#pragma unroll
    for (int kt = 0; kt < 4; ++kt)
        bx[kt] = *reinterpret_cast<const f16x8*>(
            &xs[lane & 15][kt * 32 + (lane >> 4) * 8]);

    const __half* wbase = Wt + (size_t)w * 16384;

#pragma unroll
    for (int ct = 0; ct < 8; ++ct) {
        accf4 acc = {0.f, 0.f, 0.f, 0.f};
#pragma unroll
        for (int kt = 0; kt < 4; ++kt) {
            f16x8 af = *reinterpret_cast<const f16x8*>(
                wbase + (size_t)((ct * 4 + kt) * 64 + lane) * 8);
            acc = __builtin_amdgcn_mfma_f32_16x16x32_f16(af, bx[kt], acc, 0, 0, 0);
        }
        const float4 bb = *reinterpret_cast<const float4*>(
            bm + ct * 16 + ((lane >> 4) << 2));
        h4 o;
        o.a = __floats2half2_rn((acc[0] + bb.x) * sc, (acc[1] + bb.y) * sc);
        o.b = __floats2half2_rn((acc[2] + bb.z) * sc, (acc[3] + bb.w) * sc);
        *reinterpret_cast<h4*>(
            &ys[lane & 15][w * 128 + ct * 16 + ((lane >> 4) << 2)]) = o;
    }
    __syncthreads();

    // write out contiguous fp16 rows (1KB per wave per stream)
    {
        const int node = tid >> 4;
        const int c8 = (tid & 15) * 8;
        h8 q = *reinterpret_cast<h8*>(&ys[node][c8]);
        h8 k = *reinterpret_cast<h8*>(&ys[node][128 + c8]);
        h8 v = *reinterpret_cast<h8*>(&ys[node][256 + c8]);
        h8 s = *reinterpret_cast<h8*>(&ys[node][384 + c8]);
        *reinterpret_cast<h8*>(Qh + (size_t)(n0 + node) * 128 + c8) = q;
        *reinterpret_cast<h8*>(KV + (size_t)(n0 + node) * 256 + c8) = k;
        *reinterpret_cast<h8*>(KV + (size_t)(n0 + node) * 256 + 128 + c8) = v;
        *reinterpret_cast<h8*>(Sh + (size_t)(n0 + node) * 128 + c8) = s;
    }
}

// ---------------------------------------------------------------------------
// Kernel 2: degree histogram over dst
// ---------------------------------------------------------------------------
__global__ __launch_bounds__(256) void deg_kernel(const int* __restrict__ ei,
                                                  int* __restrict__ deg)
{
    int e = blockIdx.x * 256 + threadIdx.x;
    if (e < EE) atomicAdd(&deg[ei[EE + e]], 1);
}

// ---------------------------------------------------------------------------
// Kernels 3a/3b/3c: hierarchical exclusive scan of deg -> offs (+cursor copy)
// ---------------------------------------------------------------------------
#define SC_BLK 1024
#define SC_NB ((NN + SC_BLK - 1) / SC_BLK)   // 98

__global__ __launch_bounds__(256) void scanA_kernel(const int* __restrict__ deg,
                                                    int* __restrict__ offs,
                                                    int* __restrict__ bsum)
{
    __shared__ int wsum[4];
    const int tid = threadIdx.x;
    const int lane = tid & 63;
    const int wid = tid >> 6;
    const int base = blockIdx.x * SC_BLK + tid * 4;

    int v[4];
#pragma unroll
    for (int j = 0; j < 4; ++j) v[j] = (base + j < NN) ? deg[base + j] : 0;
    int s = v[0] + v[1] + v[2] + v[3];

    int inc = s;
#pragma unroll
    for (int off = 1; off < 64; off <<= 1) {
        int t = __shfl_up(inc, off);
        if (lane >= off) inc += t;
    }
    if (lane == 63) wsum[wid] = inc;
    __syncthreads();

    int wbase = 0;
    if (wid > 0) wbase += wsum[0];
    if (wid > 1) wbase += wsum[1];
    if (wid > 2) wbase += wsum[2];

    int excl = wbase + inc - s;
#pragma unroll
    for (int j = 0; j < 4; ++j) {
        if (base + j < NN) offs[base + j] = excl;
        excl += v[j];
    }
    if (tid == 255) bsum[blockIdx.x] = wbase + inc;
}

__global__ __launch_bounds__(128) void scanB_kernel(int* __restrict__ bsum)
{
    __shared__ int w0;
    const int tid = threadIdx.x;
    const int lane = tid & 63;
    int v = (tid < SC_NB) ? bsum[tid] : 0;
    int inc = v;
#pragma unroll
    for (int off = 1; off < 64; off <<= 1) {
        int t = __shfl_up(inc, off);
        if (lane >= off) inc += t;
    }
    if (tid == 63) w0 = inc;
    __syncthreads();
    int excl = inc - v + ((tid >= 64) ? w0 : 0);
    if (tid < SC_NB) bsum[tid] = excl;
}

__global__ __launch_bounds__(256) void scanC_kernel(int* __restrict__ offs,
                                                    const int* __restrict__ bsum,
                                                    int* __restrict__ cursor)
{
    int i = blockIdx.x * 256 + threadIdx.x;
    if (i < NN) {
        int v = offs[i] + bsum[i >> 10];
        offs[i] = v;
        cursor[i] = v;
    }
}

// ---------------------------------------------------------------------------
// Kernel 4: scatter edges into dst-sorted order (store src index)
// ---------------------------------------------------------------------------
__global__ __launch_bounds__(256) void scatter_kernel(const int* __restrict__ ei,
                                                      int* __restrict__ cursor,
                                                      int* __restrict__ ssrc)
{
    int e = blockIdx.x * 256 + threadIdx.x;
    if (e < EE) {
        int dst = ei[EE + e];
        int pos = atomicAdd(&cursor[dst], 1);
        ssrc[pos] = ei[e];
    }
}

// ---------------------------------------------------------------------------
// Kernel 5: per-node attention (no-max softmax: scores bounded |p|<~2) +
// skip + tanh + readout MLP.
// One wave per node. Lane layout: eg = lane>>4 (edge slot 0..3),
// li = lane&15 (row position, dims 8*li..8*li+7; head = li>>2).
// Per iteration the wave processes 4 edges; each lane loads 16B of K and 16B
// of V (1KB coalesced per load instr). Dot-reduce: 2 shfl_xor within quads.
// Cross-slot combine (xor 16,32) once at the end.
// ---------------------------------------------------------------------------
__global__ __launch_bounds__(256) void attn_kernel(
    const __half* __restrict__ Qh, const __half* __restrict__ KV,
    const __half* __restrict__ Sh,
    const int* __restrict__ offs, const int* __restrict__ deg,
    const int* __restrict__ ssrc,
    const float* __restrict__ W1, const float* __restrict__ b1,
    const float* __restrict__ W2, const float* __restrict__ b2,
    const float* __restrict__ W3, const float* __restrict__ b3,
    float* __restrict__ out)
{
    const int wid = threadIdx.x >> 6;
    const int lane = threadIdx.x & 63;
    const int node = blockIdx.x * 4 + wid;
    const int eg = lane >> 4;   // edge slot
    const int li = lane & 15;   // position within row

    __shared__ float hs[4][128];
    __shared__ float h1s[4][24];
    __shared__ float h2s[4][8];

    // q dims 8*li .. 8*li+7 (already scaled by 1/sqrt(32) at projection)
    float qf[8];
    {
        const h8 qq = *reinterpret_cast<const h8*>(Qh + (size_t)node * 128 + li * 8);
#pragma unroll
        for (int j = 0; j < 4; ++j) {
            const float2 f = __half22float2(qq.h[j]);
            qf[2 * j] = f.x;
            qf[2 * j + 1] = f.y;
        }
    }

    float a[8];
#pragma unroll
    for (int j = 0; j < 8; ++j) a[j] = 0.f;
    float l = 0.f;

    const int st = offs[node];
    const int dg = deg[node];

    for (int it = 0; it < dg; it += 4) {
        const int e = it + eg;
        const bool valid = e < dg;
        const int src = ssrc[valid ? (st + e) : st];
        const __half* row = KV + (size_t)src * 256 + li * 8;

        const h8 kk = *reinterpret_cast<const h8*>(row);
        float p = 0.f;
#pragma unroll
        for (int j = 0; j < 4; ++j) {
            const float2 kf = __half22float2(kk.h[j]);
            p = fmaf(qf[2 * j], kf.x, p);
            p = fmaf(qf[2 * j + 1], kf.y, p);
        }
        p += __shfl_xor(p, 1);
        p += __shfl_xor(p, 2);   // now each lane has its head's full score

        float w = valid ? __expf(p) : 0.f;

        const h8 vv = *reinterpret_cast<const h8*>(row + 128);
        l += w;
#pragma unroll
        for (int j = 0; j < 4; ++j) {
            const float2 vf = __half22float2(vv.h[j]);
            a[2 * j]     = fmaf(w, vf.x, a[2 * j]);
            a[2 * j + 1] = fmaf(w, vf.y, a[2 * j + 1]);
        }
    }

    // combine the 4 edge slots
#pragma unroll
    for (int j = 0; j < 8; ++j) {
        a[j] += __shfl_xor(a[j], 16);
        a[j] += __shfl_xor(a[j], 32);
    }
    l += __shfl_xor(l, 16);
    l += __shfl_xor(l, 32);

    const float inv = (l > 0.f) ? 1.f / l : 0.f;

    if (eg == 0) {
        const h8 ss = *reinterpret_cast<const h8*>(Sh + (size_t)node * 128 + li * 8);
#pragma unroll
        for (int j = 0; j < 4; ++j) {
            const float2 sf = __half22float2(ss.h[j]);
            hs[wid][li * 8 + 2 * j]     = fast_tanh(a[2 * j] * inv + sf.x);
            hs[wid][li * 8 + 2 * j + 1] = fast_tanh(a[2 * j + 1] * inv + sf.y);
        }
    }
    __syncthreads();

    if (lane < 24) {
        float t = b1[lane];
#pragma unroll 8
        for (int kk = 0; kk < 128; ++kk) t = fmaf(hs[wid][kk], W1[kk * 24 + lane], t);
        h1s[wid][lane] = t - fast_tanh(t);
    }
    __syncthreads();

    if (lane < 8) {
        float u = b2[lane];
#pragma unroll
        for (int kk = 0; kk < 24; ++kk) u = fmaf(h1s[wid][kk], W2[kk * 8 + lane], u);
        h2s[wid][lane] = u - fast_tanh(u);
    }
    __syncthreads();

    if (lane < 2) {
        float o = b3[lane];
#pragma unroll
        for (int kk = 0; kk < 8; ++kk) o = fmaf(h2s[wid][kk], W3[kk * 2 + lane], o);
        out[(size_t)node * 2 + lane] = o;
    }
}

// ---------------------------------------------------------------------------
extern "C" void kernel_launch(void* const* d_in, const int* in_sizes, int n_in,
                              void* d_out, int out_size, void* d_ws, size_t ws_size,
                              hipStream_t stream)
{
    const float* x  = (const float*)d_in[0];
    const int*   ei = (const int*)d_in[1];
    const float* Wq = (const float*)d_in[2];
    const float* bq = (const float*)d_in[3];
    const float* Wk = (const float*)d_in[4];
    const float* bk = (const float*)d_in[5];
    const float* Wv = (const float*)d_in[6];
    const float* bv = (const float*)d_in[7];
    const float* Ws = (const float*)d_in[8];
    const float* bs = (const float*)d_in[9];
    const float* W1 = (const float*)d_in[10];
    const float* b1 = (const float*)d_in[11];
    const float* W2 = (const float*)d_in[12];
    const float* b2 = (const float*)d_in[13];
    const float* W3 = (const float*)d_in[14];
    const float* b3 = (const float*)d_in[15];
    float* out = (float*)d_out;

    __half* ws = (__half*)d_ws;
    __half* Qh = ws;
    __half* Sh = Qh + (size_t)NN * HD_;
    __half* KV = Sh + (size_t)NN * HD_;
    __half* Wt = KV + (size_t)NN * 256;
    int* deg    = (int*)(Wt + 65536);
    int* offs   = deg + NN;
    int* cursor = offs + NN;
    int* ssrc   = cursor + NN;
    int* bsum   = ssrc + EE;

    (void)hipMemsetAsync(deg, 0, NN * sizeof(int), stream);

    wt_kernel<<<32, 256, 0, stream>>>(Wq, Wk, Wv, Ws, Wt);
    proj_mfma<<<NN / 16, 256, 0, stream>>>(x, Wt, bq, bk, bv, bs, Qh, Sh, KV);
    deg_kernel<<<(EE + 255) / 256, 256, 0, stream>>>(ei, deg);
    scanA_kernel<<<SC_NB, 256, 0, stream>>>(deg, offs, bsum);
    scanB_kernel<<<1, 128, 0, stream>>>(bsum);
    scanC_kernel<<<(NN + 255) / 256, 256, 0, stream>>>(offs, bsum, cursor);
    scatter_kernel<<<(EE + 255) / 256, 256, 0, stream>>>(ei, cursor, ssrc);
    attn_kernel<<<NN / 4, 256, 0, stream>>>(Qh, KV, Sh, offs, deg, ssrc,
                                            W1, b1, W2, b2, W3, b3, out);
}

// Round 8
// 404.107 us; speedup vs baseline: 1.5161x; 1.1269x over previous
//
#include <hip/hip_runtime.h>
#include <hip/hip_bf16.h>
#include <hip/hip_fp16.h>
#include <math.h>

#define NN 100000
#define EE 1600000
#define HD_ 128   // heads*hid = 4*32

typedef float f32x4 __attribute__((ext_vector_type(4)));
typedef _Float16 f16x8 __attribute__((ext_vector_type(8)));
typedef float accf4 __attribute__((ext_vector_type(4)));

// ---------------------------------------------------------------------------
// fast tanh via hardware exp, overflow-safe form
// ---------------------------------------------------------------------------
__device__ __forceinline__ float fast_tanh(float z) {
    float az = fabsf(z);
    float e = __expf(-2.f * az);
    float t = (1.f - e) / (1.f + e);
    return copysignf(t, z);
}

struct alignas(16) h8 { __half2 h[4]; };  // 8 halves = 16B
struct alignas(8)  h4 { __half2 a, b; };  // 4 halves = 8B

// ---------------------------------------------------------------------------
// Kernel 0: one-time W transpose/convert into MFMA A-fragment layout (fp16).
// Frag index: (((mat*8 + ct)*4 + kt)*64 + lane)*8 + j
//   element = W_mat[kt*32 + (lane>>4)*8 + j][ct*16 + (lane&15)]
// ---------------------------------------------------------------------------
__global__ __launch_bounds__(256) void wt_kernel(
    const float* __restrict__ Wq, const float* __restrict__ Wk,
    const float* __restrict__ Wv, const float* __restrict__ Ws,
    __half* __restrict__ Wt)
{
    const int t = blockIdx.x * 256 + threadIdx.x;   // 0..8191
    const int lane = t & 63;
    const int kt = (t >> 6) & 3;
    const int ct = (t >> 8) & 7;
    const int mat = t >> 11;
    const float* Wm = (mat == 0) ? Wq : (mat == 1) ? Wk : (mat == 2) ? Wv : Ws;
    const int col = ct * 16 + (lane & 15);
    const int k0 = kt * 32 + (lane >> 4) * 8;
    h8 hh;
#pragma unroll
    for (int j = 0; j < 4; ++j) {
        hh.h[j] = __floats2half2_rn(Wm[(size_t)(k0 + 2 * j) * 128 + col],
                                    Wm[(size_t)(k0 + 2 * j + 1) * 128 + col]);
    }
    *reinterpret_cast<h8*>(Wt + (size_t)t * 8) = hh;
}

// ---------------------------------------------------------------------------
// Kernel 1: fused projections via MFMA (fp16 in, fp32 acc, fp16 out).
// Block = 256 = 4 waves; wave w owns matrix w (0:Q, 1:K, 2:V, 3:S).
// 16 nodes/block. Lane holds node=lane&15, out-cols ct*16+(lane>>4)*4+r.
// ---------------------------------------------------------------------------
__global__ __launch_bounds__(256) void proj_mfma(
    const float* __restrict__ x, const __half* __restrict__ Wt,
    const float* __restrict__ bq, const float* __restrict__ bk,
    const float* __restrict__ bv, const float* __restrict__ bs,
    __half* __restrict__ Qh, __half* __restrict__ Sh, __half* __restrict__ KV)
{
    __shared__ __half xs[16][136];   // x tile fp16, padded stride
    __shared__ __half ys[16][520];   // output staging [node][mat*128+col]
    const int tid = threadIdx.x;
    const int n0 = blockIdx.x * 16;

    // stage x[16][128] -> fp16 LDS
    {
        const int row = tid & 15;
        const int k0 = (tid >> 4) * 8;
        const f32x4* xp = reinterpret_cast<const f32x4*>(
            x + (size_t)(n0 + row) * 128 + k0);
        f32x4 a = __builtin_nontemporal_load(xp);
        f32x4 b = __builtin_nontemporal_load(xp + 1);
        h8 hh;
        hh.h[0] = __floats2half2_rn(a.x, a.y);
        hh.h[1] = __floats2half2_rn(a.z, a.w);
        hh.h[2] = __floats2half2_rn(b.x, b.y);
        hh.h[3] = __floats2half2_rn(b.z, b.w);
        *reinterpret_cast<h8*>(&xs[row][k0]) = hh;
    }
    __syncthreads();

    const int w = tid >> 6;     // matrix
    const int lane = tid & 63;
    const float* bm = (w == 0) ? bq : (w == 1) ? bk : (w == 2) ? bv : bs;
    const float sc = (w == 0) ? 0.17677669529663687f : 1.f;  // 1/sqrt(32)

    f16x8 bx[4];
#pragma unroll
    for (int kt = 0; kt < 4; ++kt)
        bx[kt] = *reinterpret_cast<const f16x8*>(
            &xs[lane & 15][kt * 32 + (lane >> 4) * 8]);

    const __half* wbase = Wt + (size_t)w * 16384;

#pragma unroll
    for (int ct = 0; ct < 8; ++ct) {
        accf4 acc = {0.f, 0.f, 0.f, 0.f};
#pragma unroll
        for (int kt = 0; kt < 4; ++kt) {
            f16x8 af = *reinterpret_cast<const f16x8*>(
                wbase + (size_t)((ct * 4 + kt) * 64 + lane) * 8);
            acc = __builtin_amdgcn_mfma_f32_16x16x32_f16(af, bx[kt], acc, 0, 0, 0);
        }
        const float4 bb = *reinterpret_cast<const float4*>(
            bm + ct * 16 + ((lane >> 4) << 2));
        h4 o;
        o.a = __floats2half2_rn((acc[0] + bb.x) * sc, (acc[1] + bb.y) * sc);
        o.b = __floats2half2_rn((acc[2] + bb.z) * sc, (acc[3] + bb.w) * sc);
        *reinterpret_cast<h4*>(
            &ys[lane & 15][w * 128 + ct * 16 + ((lane >> 4) << 2)]) = o;
    }
    __syncthreads();

    // write out contiguous fp16 rows
    {
        const int node = tid >> 4;
        const int c8 = (tid & 15) * 8;
        h8 q = *reinterpret_cast<h8*>(&ys[node][c8]);
        h8 k = *reinterpret_cast<h8*>(&ys[node][128 + c8]);
        h8 v = *reinterpret_cast<h8*>(&ys[node][256 + c8]);
        h8 s = *reinterpret_cast<h8*>(&ys[node][384 + c8]);
        *reinterpret_cast<h8*>(Qh + (size_t)(n0 + node) * 128 + c8) = q;
        *reinterpret_cast<h8*>(KV + (size_t)(n0 + node) * 256 + c8) = k;
        *reinterpret_cast<h8*>(KV + (size_t)(n0 + node) * 256 + 128 + c8) = v;
        *reinterpret_cast<h8*>(Sh + (size_t)(n0 + node) * 128 + c8) = s;
    }
}

// ---------------------------------------------------------------------------
// Kernel 2: degree histogram over dst
// ---------------------------------------------------------------------------
__global__ __launch_bounds__(256) void deg_kernel(const int* __restrict__ ei,
                                                  int* __restrict__ deg)
{
    int e = blockIdx.x * 256 + threadIdx.x;
    if (e < EE) atomicAdd(&deg[ei[EE + e]], 1);
}

// ---------------------------------------------------------------------------
// Kernels 3a/3b/3c: hierarchical exclusive scan of deg -> offs (+cursor copy)
// ---------------------------------------------------------------------------
#define SC_BLK 1024
#define SC_NB ((NN + SC_BLK - 1) / SC_BLK)   // 98

__global__ __launch_bounds__(256) void scanA_kernel(const int* __restrict__ deg,
                                                    int* __restrict__ offs,
                                                    int* __restrict__ bsum)
{
    __shared__ int wsum[4];
    const int tid = threadIdx.x;
    const int lane = tid & 63;
    const int wid = tid >> 6;
    const int base = blockIdx.x * SC_BLK + tid * 4;

    int v[4];
#pragma unroll
    for (int j = 0; j < 4; ++j) v[j] = (base + j < NN) ? deg[base + j] : 0;
    int s = v[0] + v[1] + v[2] + v[3];

    int inc = s;
#pragma unroll
    for (int off = 1; off < 64; off <<= 1) {
        int t = __shfl_up(inc, off);
        if (lane >= off) inc += t;
    }
    if (lane == 63) wsum[wid] = inc;
    __syncthreads();

    int wbase = 0;
    if (wid > 0) wbase += wsum[0];
    if (wid > 1) wbase += wsum[1];
    if (wid > 2) wbase += wsum[2];

    int excl = wbase + inc - s;
#pragma unroll
    for (int j = 0; j < 4; ++j) {
        if (base + j < NN) offs[base + j] = excl;
        excl += v[j];
    }
    if (tid == 255) bsum[blockIdx.x] = wbase + inc;
}

__global__ __launch_bounds__(128) void scanB_kernel(int* __restrict__ bsum)
{
    __shared__ int w0;
    const int tid = threadIdx.x;
    const int lane = tid & 63;
    int v = (tid < SC_NB) ? bsum[tid] : 0;
    int inc = v;
#pragma unroll
    for (int off = 1; off < 64; off <<= 1) {
        int t = __shfl_up(inc, off);
        if (lane >= off) inc += t;
    }
    if (tid == 63) w0 = inc;
    __syncthreads();
    int excl = inc - v + ((tid >= 64) ? w0 : 0);
    if (tid < SC_NB) bsum[tid] = excl;
}

__global__ __launch_bounds__(256) void scanC_kernel(int* __restrict__ offs,
                                                    const int* __restrict__ bsum,
                                                    int* __restrict__ cursor)
{
    int i = blockIdx.x * 256 + threadIdx.x;
    if (i < NN) {
        int v = offs[i] + bsum[i >> 10];
        offs[i] = v;
        cursor[i] = v;
    }
}

// ---------------------------------------------------------------------------
// Kernel 4: scatter edges into dst-sorted order (store src index)
// ---------------------------------------------------------------------------
__global__ __launch_bounds__(256) void scatter_kernel(const int* __restrict__ ei,
                                                      int* __restrict__ cursor,
                                                      int* __restrict__ ssrc)
{
    int e = blockIdx.x * 256 + threadIdx.x;
    if (e < EE) {
        int dst = ei[EE + e];
        int pos = atomicAdd(&cursor[dst], 1);
        ssrc[pos] = ei[e];
    }
}

// ---------------------------------------------------------------------------
// Kernel 5: per-node attention (no-max softmax) + skip + tanh -> h (fp16).
// One wave per node, NO LDS, no syncs. Lane: eg = lane>>4 (edge slot),
// li = lane&15 (dims 8*li..8*li+7). 8 edges per iteration in two 4-edge
// batches A/B: 1 ssrc round-trip + 4 independent 16B K/V loads in flight.
// ---------------------------------------------------------------------------
__global__ __launch_bounds__(256) void attn_kernel(
    const __half* __restrict__ Qh, const __half* __restrict__ KV,
    const __half* __restrict__ Sh,
    const int* __restrict__ offs, const int* __restrict__ deg,
    const int* __restrict__ ssrc,
    __half* __restrict__ hbuf)
{
    const int wid = threadIdx.x >> 6;
    const int lane = threadIdx.x & 63;
    const int node = blockIdx.x * 4 + wid;
    const int eg = lane >> 4;   // edge slot
    const int li = lane & 15;   // position within row

    // q dims 8*li .. 8*li+7 (already scaled by 1/sqrt(32) at projection)
    float qf[8];
    {
        const h8 qq = *reinterpret_cast<const h8*>(Qh + (size_t)node * 128 + li * 8);
#pragma unroll
        for (int j = 0; j < 4; ++j) {
            const float2 f = __half22float2(qq.h[j]);
            qf[2 * j] = f.x;
            qf[2 * j + 1] = f.y;
        }
    }

    float a[8];
#pragma unroll
    for (int j = 0; j < 8; ++j) a[j] = 0.f;
    float l = 0.f;

    const int st = offs[node];
    const int dg = deg[node];

    for (int it = 0; it < dg; it += 8) {
        const int eA = it + eg;
        const int eB = it + 4 + eg;
        const bool vA = eA < dg;
        const bool vB = eB < dg;
        const int srcA = ssrc[st + (vA ? eA : 0)];
        const int srcB = ssrc[st + (vB ? eB : 0)];
        const __half* rA = KV + (size_t)srcA * 256 + li * 8;
        const __half* rB = KV + (size_t)srcB * 256 + li * 8;

        const h8 kA = *reinterpret_cast<const h8*>(rA);
        const h8 vA2 = *reinterpret_cast<const h8*>(rA + 128);
        const h8 kB = *reinterpret_cast<const h8*>(rB);
        const h8 vB2 = *reinterpret_cast<const h8*>(rB + 128);

        float pA = 0.f, pB = 0.f;
#pragma unroll
        for (int j = 0; j < 4; ++j) {
            const float2 ka = __half22float2(kA.h[j]);
            const float2 kb = __half22float2(kB.h[j]);
            pA = fmaf(qf[2 * j], ka.x, pA);
            pA = fmaf(qf[2 * j + 1], ka.y, pA);
            pB = fmaf(qf[2 * j], kb.x, pB);
            pB = fmaf(qf[2 * j + 1], kb.y, pB);
        }
        pA += __shfl_xor(pA, 1);
        pA += __shfl_xor(pA, 2);
        pB += __shfl_xor(pB, 1);
        pB += __shfl_xor(pB, 2);

        const float wA = vA ? __expf(pA) : 0.f;
        const float wB = vB ? __expf(pB) : 0.f;
        l += wA + wB;
#pragma unroll
        for (int j = 0; j < 4; ++j) {
            const float2 va = __half22float2(vA2.h[j]);
            const float2 vb = __half22float2(vB2.h[j]);
            a[2 * j]     = fmaf(wA, va.x, a[2 * j]);
            a[2 * j + 1] = fmaf(wA, va.y, a[2 * j + 1]);
            a[2 * j]     = fmaf(wB, vb.x, a[2 * j]);
            a[2 * j + 1] = fmaf(wB, vb.y, a[2 * j + 1]);
        }
    }

    // combine the 4 edge slots
#pragma unroll
    for (int j = 0; j < 8; ++j) {
        a[j] += __shfl_xor(a[j], 16);
        a[j] += __shfl_xor(a[j], 32);
    }
    l += __shfl_xor(l, 16);
    l += __shfl_xor(l, 32);

    const float inv = (l > 0.f) ? 1.f / l : 0.f;

    if (eg == 0) {
        const h8 ss = *reinterpret_cast<const h8*>(Sh + (size_t)node * 128 + li * 8);
        h8 ho;
#pragma unroll
        for (int j = 0; j < 4; ++j) {
            const float2 sf = __half22float2(ss.h[j]);
            const float h0 = fast_tanh(a[2 * j] * inv + sf.x);
            const float h1 = fast_tanh(a[2 * j + 1] * inv + sf.y);
            ho.h[j] = __floats2half2_rn(h0, h1);
        }
        *reinterpret_cast<h8*>(hbuf + (size_t)node * 128 + li * 8) = ho;
    }
}

// ---------------------------------------------------------------------------
// Kernel 6: readout MLP  out = W3ᵀ(ts(W2ᵀ(ts(W1ᵀ h + b1)) + b2)) + b3
// (ts = tanhshrink). One thread per node; W1/W2/W3/biases staged in LDS
// (broadcast reads, conflict-free). h read as fp16 in 8-chunks.
// ---------------------------------------------------------------------------
__global__ __launch_bounds__(256) void mlp_kernel(
    const __half* __restrict__ hbuf,
    const float* __restrict__ W1, const float* __restrict__ b1,
    const float* __restrict__ W2, const float* __restrict__ b2,
    const float* __restrict__ W3, const float* __restrict__ b3,
    float* __restrict__ out)
{
    __shared__ float W1s[128][24];   // [k][j]
    __shared__ float W2s[24][8];
    __shared__ float W3s[8][2];
    __shared__ float b1s[24], b2s[8], b3s[2];

    const int tid = threadIdx.x;

    // stage weights
    {
        const float4* src = reinterpret_cast<const float4*>(W1 + tid * 12);
        float4* dst = reinterpret_cast<float4*>(&W1s[0][0] + tid * 12);
        dst[0] = src[0];
        dst[1] = src[1];
        dst[2] = src[2];
        if (tid < 48)
            reinterpret_cast<float4*>(&W2s[0][0])[tid] =
                reinterpret_cast<const float4*>(W2)[tid];
        if (tid < 4)
            reinterpret_cast<float4*>(&W3s[0][0])[tid] =
                reinterpret_cast<const float4*>(W3)[tid];
        if (tid < 24) b1s[tid] = b1[tid];
        if (tid < 8)  b2s[tid] = b2[tid];
        if (tid < 2)  b3s[tid] = b3[tid];
    }
    __syncthreads();

    const int node = blockIdx.x * 256 + tid;
    if (node >= NN) return;

    float t24[24];
#pragma unroll
    for (int j = 0; j < 24; ++j) t24[j] = b1s[j];

    const h8* hrow = reinterpret_cast<const h8*>(hbuf + (size_t)node * 128);
#pragma unroll
    for (int c = 0; c < 16; ++c) {
        const h8 hh = hrow[c];
        float hf[8];
#pragma unroll
        for (int j = 0; j < 4; ++j) {
            const float2 f = __half22float2(hh.h[j]);
            hf[2 * j] = f.x;
            hf[2 * j + 1] = f.y;
        }
#pragma unroll
        for (int i = 0; i < 8; ++i) {
            const int kk = c * 8 + i;
#pragma unroll
            for (int j4 = 0; j4 < 6; ++j4) {
                const float4 w4 = *reinterpret_cast<const float4*>(&W1s[kk][j4 * 4]);
                t24[j4 * 4 + 0] = fmaf(hf[i], w4.x, t24[j4 * 4 + 0]);
                t24[j4 * 4 + 1] = fmaf(hf[i], w4.y, t24[j4 * 4 + 1]);
                t24[j4 * 4 + 2] = fmaf(hf[i], w4.z, t24[j4 * 4 + 2]);
                t24[j4 * 4 + 3] = fmaf(hf[i], w4.w, t24[j4 * 4 + 3]);
            }
        }
    }

    float u8[8];
#pragma unroll
    for (int j = 0; j < 8; ++j) u8[j] = b2s[j];
#pragma unroll
    for (int kk = 0; kk < 24; ++kk) {
        const float hv = t24[kk] - fast_tanh(t24[kk]);
#pragma unroll
        for (int j = 0; j < 8; ++j) u8[j] = fmaf(hv, W2s[kk][j], u8[j]);
    }

    float o0 = b3s[0], o1 = b3s[1];
#pragma unroll
    for (int kk = 0; kk < 8; ++kk) {
        const float hv = u8[kk] - fast_tanh(u8[kk]);
        o0 = fmaf(hv, W3s[kk][0], o0);
        o1 = fmaf(hv, W3s[kk][1], o1);
    }
    *reinterpret_cast<float2*>(out + (size_t)node * 2) = make_float2(o0, o1);
}

// ---------------------------------------------------------------------------
extern "C" void kernel_launch(void* const* d_in, const int* in_sizes, int n_in,
                              void* d_out, int out_size, void* d_ws, size_t ws_size,
                              hipStream_t stream)
{
    const float* x  = (const float*)d_in[0];
    const int*   ei = (const int*)d_in[1];
    const float* Wq = (const float*)d_in[2];
    const float* bq = (const float*)d_in[3];
    const float* Wk = (const float*)d_in[4];
    const float* bk = (const float*)d_in[5];
    const float* Wv = (const float*)d_in[6];
    const float* bv = (const float*)d_in[7];
    const float* Ws = (const float*)d_in[8];
    const float* bs = (const float*)d_in[9];
    const float* W1 = (const float*)d_in[10];
    const float* b1 = (const float*)d_in[11];
    const float* W2 = (const float*)d_in[12];
    const float* b2 = (const float*)d_in[13];
    const float* W3 = (const float*)d_in[14];
    const float* b3 = (const float*)d_in[15];
    float* out = (float*)d_out;

    __half* ws = (__half*)d_ws;
    __half* Qh = ws;
    __half* Sh = Qh + (size_t)NN * HD_;
    __half* KV = Sh + (size_t)NN * HD_;
    __half* hbuf = KV + (size_t)NN * 256;
    __half* Wt = hbuf + (size_t)NN * HD_;
    int* deg    = (int*)(Wt + 65536);
    int* offs   = deg + NN;
    int* cursor = offs + NN;
    int* ssrc   = cursor + NN;
    int* bsum   = ssrc + EE;

    (void)hipMemsetAsync(deg, 0, NN * sizeof(int), stream);

    wt_kernel<<<32, 256, 0, stream>>>(Wq, Wk, Wv, Ws, Wt);
    proj_mfma<<<NN / 16, 256, 0, stream>>>(x, Wt, bq, bk, bv, bs, Qh, Sh, KV);
    deg_kernel<<<(EE + 255) / 256, 256, 0, stream>>>(ei, deg);
    scanA_kernel<<<SC_NB, 256, 0, stream>>>(deg, offs, bsum);
    scanB_kernel<<<1, 128, 0, stream>>>(bsum);
    scanC_kernel<<<(NN + 255) / 256, 256, 0, stream>>>(offs, bsum, cursor);
    scatter_kernel<<<(EE + 255) / 256, 256, 0, stream>>>(ei, cursor, ssrc);
    attn_kernel<<<NN / 4, 256, 0, stream>>>(Qh, KV, Sh, offs, deg, ssrc, hbuf);
    mlp_kernel<<<(NN + 255) / 256, 256, 0, stream>>>(hbuf, W1, b1, W2, b2,
                                                     W3, b3, out);
}

// Round 9
// 354.195 us; speedup vs baseline: 1.7297x; 1.1409x over previous
//
#include <hip/hip_runtime.h>
#include <hip/hip_bf16.h>
#include <hip/hip_fp16.h>
#include <math.h>

#define NN 100000
#define EE 1600000
#define HD_ 128   // heads*hid = 4*32
#define PART 8            // dst-range groups (XCD count)
#define RNG 12500         // NN / PART
#define PBLK 128          // blocks per group
#define PSTRIDE (PBLK * 256)

typedef float f32x4 __attribute__((ext_vector_type(4)));
typedef _Float16 f16x8 __attribute__((ext_vector_type(8)));
typedef float accf4 __attribute__((ext_vector_type(4)));

// ---------------------------------------------------------------------------
// fast tanh via hardware exp, overflow-safe form
// ---------------------------------------------------------------------------
__device__ __forceinline__ float fast_tanh(float z) {
    float az = fabsf(z);
    float e = __expf(-2.f * az);
    float t = (1.f - e) / (1.f + e);
    return copysignf(t, z);
}

struct alignas(16) h8 { __half2 h[4]; };  // 8 halves = 16B
struct alignas(8)  h4 { __half2 a, b; };  // 4 halves = 8B

// ---------------------------------------------------------------------------
// Kernel 0: one-time W transpose/convert into MFMA A-fragment layout (fp16).
// ---------------------------------------------------------------------------
__global__ __launch_bounds__(256) void wt_kernel(
    const float* __restrict__ Wq, const float* __restrict__ Wk,
    const float* __restrict__ Wv, const float* __restrict__ Ws,
    __half* __restrict__ Wt)
{
    const int t = blockIdx.x * 256 + threadIdx.x;   // 0..8191
    const int lane = t & 63;
    const int kt = (t >> 6) & 3;
    const int ct = (t >> 8) & 7;
    const int mat = t >> 11;
    const float* Wm = (mat == 0) ? Wq : (mat == 1) ? Wk : (mat == 2) ? Wv : Ws;
    const int col = ct * 16 + (lane & 15);
    const int k0 = kt * 32 + (lane >> 4) * 8;
    h8 hh;
#pragma unroll
    for (int j = 0; j < 4; ++j) {
        hh.h[j] = __floats2half2_rn(Wm[(size_t)(k0 + 2 * j) * 128 + col],
                                    Wm[(size_t)(k0 + 2 * j + 1) * 128 + col]);
    }
    *reinterpret_cast<h8*>(Wt + (size_t)t * 8) = hh;
}

// ---------------------------------------------------------------------------
// Kernel 1: fused projections via MFMA (fp16 in, fp32 acc, fp16 out).
// ---------------------------------------------------------------------------
__global__ __launch_bounds__(256) void proj_mfma(
    const float* __restrict__ x, const __half* __restrict__ Wt,
    const float* __restrict__ bq, const float* __restrict__ bk,
    const float* __restrict__ bv, const float* __restrict__ bs,
    __half* __restrict__ Qh, __half* __restrict__ Sh, __half* __restrict__ KV)
{
    __shared__ __half xs[16][136];   // x tile fp16, padded stride
    __shared__ __half ys[16][520];   // output staging [node][mat*128+col]
    const int tid = threadIdx.x;
    const int n0 = blockIdx.x * 16;

    // stage x[16][128] -> fp16 LDS
    {
        const int row = tid & 15;
        const int k0 = (tid >> 4) * 8;
        const f32x4* xp = reinterpret_cast<const f32x4*>(
            x + (size_t)(n0 + row) * 128 + k0);
        f32x4 a = __builtin_nontemporal_load(xp);
        f32x4 b = __builtin_nontemporal_load(xp + 1);
        h8 hh;
        hh.h[0] = __floats2half2_rn(a.x, a.y);
        hh.h[1] = __floats2half2_rn(a.z, a.w);
        hh.h[2] = __floats2half2_rn(b.x, b.y);
        hh.h[3] = __floats2half2_rn(b.z, b.w);
        *reinterpret_cast<h8*>(&xs[row][k0]) = hh;
    }
    __syncthreads();

    const int w = tid >> 6;     // matrix
    const int lane = tid & 63;
    const float* bm = (w == 0) ? bq : (w == 1) ? bk : (w == 2) ? bv : bs;
    const float sc = (w == 0) ? 0.17677669529663687f : 1.f;  // 1/sqrt(32)

    f16x8 bx[4];
#pragma unroll
    for (int kt = 0; kt < 4; ++kt)
        bx[kt] = *reinterpret_cast<const f16x8*>(
            &xs[lane & 15][kt * 32 + (lane >> 4) * 8]);

    const __half* wbase = Wt + (size_t)w * 16384;

#pragma unroll
    for (int ct = 0; ct < 8; ++ct) {
        accf4 acc = {0.f, 0.f, 0.f, 0.f};
#pragma unroll
        for (int kt = 0; kt < 4; ++kt) {
            f16x8 af = *reinterpret_cast<const f16x8*>(
                wbase + (size_t)((ct * 4 + kt) * 64 + lane) * 8);
            acc = __builtin_amdgcn_mfma_f32_16x16x32_f16(af, bx[kt], acc, 0, 0, 0);
        }
        const float4 bb = *reinterpret_cast<const float4*>(
            bm + ct * 16 + ((lane >> 4) << 2));
        h4 o;
        o.a = __floats2half2_rn((acc[0] + bb.x) * sc, (acc[1] + bb.y) * sc);
        o.b = __floats2half2_rn((acc[2] + bb.z) * sc, (acc[3] + bb.w) * sc);
        *reinterpret_cast<h4*>(
            &ys[lane & 15][w * 128 + ct * 16 + ((lane >> 4) << 2)]) = o;
    }
    __syncthreads();

    // write out contiguous fp16 rows
    {
        const int node = tid >> 4;
        const int c8 = (tid & 15) * 8;
        h8 q = *reinterpret_cast<h8*>(&ys[node][c8]);
        h8 k = *reinterpret_cast<h8*>(&ys[node][128 + c8]);
        h8 v = *reinterpret_cast<h8*>(&ys[node][256 + c8]);
        h8 s = *reinterpret_cast<h8*>(&ys[node][384 + c8]);
        *reinterpret_cast<h8*>(Qh + (size_t)(n0 + node) * 128 + c8) = q;
        *reinterpret_cast<h8*>(KV + (size_t)(n0 + node) * 256 + c8) = k;
        *reinterpret_cast<h8*>(KV + (size_t)(n0 + node) * 256 + 128 + c8) = v;
        *reinterpret_cast<h8*>(Sh + (size_t)(n0 + node) * 128 + c8) = s;
    }
}

// ---------------------------------------------------------------------------
// Kernel 2: degree histogram over dst — 8-way dst-range partitioned so each
// deg cache line is written (atomically) from one XCD group only.
// ---------------------------------------------------------------------------
__global__ __launch_bounds__(256) void deg_kernel(const int* __restrict__ ei,
                                                  int* __restrict__ deg)
{
    const int g = blockIdx.x & (PART - 1);
    const int bg = blockIdx.x >> 3;
    const int lo = g * RNG;
    const int hi = lo + RNG;   // NN = PART*RNG exactly
    for (int e = bg * 256 + threadIdx.x; e < EE; e += PSTRIDE) {
        const int d = ei[EE + e];
        if (d >= lo && d < hi) atomicAdd(&deg[d], 1);
    }
}

// ---------------------------------------------------------------------------
// Kernels 3a/3b/3c: hierarchical exclusive scan of deg -> offs (+cursor copy)
// ---------------------------------------------------------------------------
#define SC_BLK 1024
#define SC_NB ((NN + SC_BLK - 1) / SC_BLK)   // 98

__global__ __launch_bounds__(256) void scanA_kernel(const int* __restrict__ deg,
                                                    int* __restrict__ offs,
                                                    int* __restrict__ bsum)
{
    __shared__ int wsum[4];
    const int tid = threadIdx.x;
    const int lane = tid & 63;
    const int wid = tid >> 6;
    const int base = blockIdx.x * SC_BLK + tid * 4;

    int v[4];
#pragma unroll
    for (int j = 0; j < 4; ++j) v[j] = (base + j < NN) ? deg[base + j] : 0;
    int s = v[0] + v[1] + v[2] + v[3];

    int inc = s;
#pragma unroll
    for (int off = 1; off < 64; off <<= 1) {
        int t = __shfl_up(inc, off);
        if (lane >= off) inc += t;
    }
    if (lane == 63) wsum[wid] = inc;
    __syncthreads();

    int wbase = 0;
    if (wid > 0) wbase += wsum[0];
    if (wid > 1) wbase += wsum[1];
    if (wid > 2) wbase += wsum[2];

    int excl = wbase + inc - s;
#pragma unroll
    for (int j = 0; j < 4; ++j) {
        if (base + j < NN) offs[base + j] = excl;
        excl += v[j];
    }
    if (tid == 255) bsum[blockIdx.x] = wbase + inc;
}

__global__ __launch_bounds__(128) void scanB_kernel(int* __restrict__ bsum)
{
    __shared__ int w0;
    const int tid = threadIdx.x;
    const int lane = tid & 63;
    int v = (tid < SC_NB) ? bsum[tid] : 0;
    int inc = v;
#pragma unroll
    for (int off = 1; off < 64; off <<= 1) {
        int t = __shfl_up(inc, off);
        if (lane >= off) inc += t;
    }
    if (tid == 63) w0 = inc;
    __syncthreads();
    int excl = inc - v + ((tid >= 64) ? w0 : 0);
    if (tid < SC_NB) bsum[tid] = excl;
}

__global__ __launch_bounds__(256) void scanC_kernel(int* __restrict__ offs,
                                                    const int* __restrict__ bsum,
                                                    int* __restrict__ cursor)
{
    int i = blockIdx.x * 256 + threadIdx.x;
    if (i < NN) {
        int v = offs[i] + bsum[i >> 10];
        offs[i] = v;
        cursor[i] = v;
    }
}

// ---------------------------------------------------------------------------
// Kernel 4: scatter edges into dst-sorted order — 8-way dst-range partitioned:
// group g only handles dst in [g*RNG,(g+1)*RNG), so every cursor/ssrc cache
// line is written from one XCD group and write-combines in its L2.
// ---------------------------------------------------------------------------
__global__ __launch_bounds__(256) void scatter_kernel(const int* __restrict__ ei,
                                                      int* __restrict__ cursor,
                                                      int* __restrict__ ssrc)
{
    const int g = blockIdx.x & (PART - 1);
    const int bg = blockIdx.x >> 3;
    const int lo = g * RNG;
    const int hi = lo + RNG;
    for (int e = bg * 256 + threadIdx.x; e < EE; e += PSTRIDE) {
        const int d = ei[EE + e];
        if (d >= lo && d < hi) {
            int pos = atomicAdd(&cursor[d], 1);
            ssrc[pos] = ei[e];
        }
    }
}

// ---------------------------------------------------------------------------
// Kernel 5: per-node attention (no-max softmax) + skip + tanh -> h (fp16).
// One wave per node, NO LDS. 8 edges/iteration in two 4-edge batches.
// ---------------------------------------------------------------------------
__global__ __launch_bounds__(256) void attn_kernel(
    const __half* __restrict__ Qh, const __half* __restrict__ KV,
    const __half* __restrict__ Sh,
    const int* __restrict__ offs, const int* __restrict__ deg,
    const int* __restrict__ ssrc,
    __half* __restrict__ hbuf)
{
    const int wid = threadIdx.x >> 6;
    const int lane = threadIdx.x & 63;
    const int node = blockIdx.x * 4 + wid;
    const int eg = lane >> 4;   // edge slot
    const int li = lane & 15;   // position within row

    float qf[8];
    {
        const h8 qq = *reinterpret_cast<const h8*>(Qh + (size_t)node * 128 + li * 8);
#pragma unroll
        for (int j = 0; j < 4; ++j) {
            const float2 f = __half22float2(qq.h[j]);
            qf[2 * j] = f.x;
            qf[2 * j + 1] = f.y;
        }
    }

    float a[8];
#pragma unroll
    for (int j = 0; j < 8; ++j) a[j] = 0.f;
    float l = 0.f;

    const int st = offs[node];
    const int dg = deg[node];

    for (int it = 0; it < dg; it += 8) {
        const int eA = it + eg;
        const int eB = it + 4 + eg;
        const bool vA = eA < dg;
        const bool vB = eB < dg;
        const int srcA = ssrc[st + (vA ? eA : 0)];
        const int srcB = ssrc[st + (vB ? eB : 0)];
        const __half* rA = KV + (size_t)srcA * 256 + li * 8;
        const __half* rB = KV + (size_t)srcB * 256 + li * 8;

        const h8 kA = *reinterpret_cast<const h8*>(rA);
        const h8 vA2 = *reinterpret_cast<const h8*>(rA + 128);
        const h8 kB = *reinterpret_cast<const h8*>(rB);
        const h8 vB2 = *reinterpret_cast<const h8*>(rB + 128);

        float pA = 0.f, pB = 0.f;
#pragma unroll
        for (int j = 0; j < 4; ++j) {
            const float2 ka = __half22float2(kA.h[j]);
            const float2 kb = __half22float2(kB.h[j]);
            pA = fmaf(qf[2 * j], ka.x, pA);
            pA = fmaf(qf[2 * j + 1], ka.y, pA);
            pB = fmaf(qf[2 * j], kb.x, pB);
            pB = fmaf(qf[2 * j + 1], kb.y, pB);
        }
        pA += __shfl_xor(pA, 1);
        pA += __shfl_xor(pA, 2);
        pB += __shfl_xor(pB, 1);
        pB += __shfl_xor(pB, 2);

        const float wA = vA ? __expf(pA) : 0.f;
        const float wB = vB ? __expf(pB) : 0.f;
        l += wA + wB;
#pragma unroll
        for (int j = 0; j < 4; ++j) {
            const float2 va = __half22float2(vA2.h[j]);
            const float2 vb = __half22float2(vB2.h[j]);
            a[2 * j]     = fmaf(wA, va.x, a[2 * j]);
            a[2 * j + 1] = fmaf(wA, va.y, a[2 * j + 1]);
            a[2 * j]     = fmaf(wB, vb.x, a[2 * j]);
            a[2 * j + 1] = fmaf(wB, vb.y, a[2 * j + 1]);
        }
    }

    // combine the 4 edge slots
#pragma unroll
    for (int j = 0; j < 8; ++j) {
        a[j] += __shfl_xor(a[j], 16);
        a[j] += __shfl_xor(a[j], 32);
    }
    l += __shfl_xor(l, 16);
    l += __shfl_xor(l, 32);

    const float inv = (l > 0.f) ? 1.f / l : 0.f;

    if (eg == 0) {
        const h8 ss = *reinterpret_cast<const h8*>(Sh + (size_t)node * 128 + li * 8);
        h8 ho;
#pragma unroll
        for (int j = 0; j < 4; ++j) {
            const float2 sf = __half22float2(ss.h[j]);
            const float h0 = fast_tanh(a[2 * j] * inv + sf.x);
            const float h1 = fast_tanh(a[2 * j + 1] * inv + sf.y);
            ho.h[j] = __floats2half2_rn(h0, h1);
        }
        *reinterpret_cast<h8*>(hbuf + (size_t)node * 128 + li * 8) = ho;
    }
}

// ---------------------------------------------------------------------------
// Kernel 6: readout MLP, one thread per node, weights staged in LDS.
// ---------------------------------------------------------------------------
__global__ __launch_bounds__(256) void mlp_kernel(
    const __half* __restrict__ hbuf,
    const float* __restrict__ W1, const float* __restrict__ b1,
    const float* __restrict__ W2, const float* __restrict__ b2,
    const float* __restrict__ W3, const float* __restrict__ b3,
    float* __restrict__ out)
{
    __shared__ float W1s[128][24];   // [k][j]
    __shared__ float W2s[24][8];
    __shared__ float W3s[8][2];
    __shared__ float b1s[24], b2s[8], b3s[2];

    const int tid = threadIdx.x;

    {
        const float4* src = reinterpret_cast<const float4*>(W1 + tid * 12);
        float4* dst = reinterpret_cast<float4*>(&W1s[0][0] + tid * 12);
        dst[0] = src[0];
        dst[1] = src[1];
        dst[2] = src[2];
        if (tid < 48)
            reinterpret_cast<float4*>(&W2s[0][0])[tid] =
                reinterpret_cast<const float4*>(W2)[tid];
        if (tid < 4)
            reinterpret_cast<float4*>(&W3s[0][0])[tid] =
                reinterpret_cast<const float4*>(W3)[tid];
        if (tid < 24) b1s[tid] = b1[tid];
        if (tid < 8)  b2s[tid] = b2[tid];
        if (tid < 2)  b3s[tid] = b3[tid];
    }
    __syncthreads();

    const int node = blockIdx.x * 256 + tid;
    if (node >= NN) return;

    float t24[24];
#pragma unroll
    for (int j = 0; j < 24; ++j) t24[j] = b1s[j];

    const h8* hrow = reinterpret_cast<const h8*>(hbuf + (size_t)node * 128);
#pragma unroll
    for (int c = 0; c < 16; ++c) {
        const h8 hh = hrow[c];
        float hf[8];
#pragma unroll
        for (int j = 0; j < 4; ++j) {
            const float2 f = __half22float2(hh.h[j]);
            hf[2 * j] = f.x;
            hf[2 * j + 1] = f.y;
        }
#pragma unroll
        for (int i = 0; i < 8; ++i) {
            const int kk = c * 8 + i;
#pragma unroll
            for (int j4 = 0; j4 < 6; ++j4) {
                const float4 w4 = *reinterpret_cast<const float4*>(&W1s[kk][j4 * 4]);
                t24[j4 * 4 + 0] = fmaf(hf[i], w4.x, t24[j4 * 4 + 0]);
                t24[j4 * 4 + 1] = fmaf(hf[i], w4.y, t24[j4 * 4 + 1]);
                t24[j4 * 4 + 2] = fmaf(hf[i], w4.z, t24[j4 * 4 + 2]);
                t24[j4 * 4 + 3] = fmaf(hf[i], w4.w, t24[j4 * 4 + 3]);
            }
        }
    }

    float u8[8];
#pragma unroll
    for (int j = 0; j < 8; ++j) u8[j] = b2s[j];
#pragma unroll
    for (int kk = 0; kk < 24; ++kk) {
        const float hv = t24[kk] - fast_tanh(t24[kk]);
#pragma unroll
        for (int j = 0; j < 8; ++j) u8[j] = fmaf(hv, W2s[kk][j], u8[j]);
    }

    float o0 = b3s[0], o1 = b3s[1];
#pragma unroll
    for (int kk = 0; kk < 8; ++kk) {
        const float hv = u8[kk] - fast_tanh(u8[kk]);
        o0 = fmaf(hv, W3s[kk][0], o0);
        o1 = fmaf(hv, W3s[kk][1], o1);
    }
    *reinterpret_cast<float2*>(out + (size_t)node * 2) = make_float2(o0, o1);
}

// ---------------------------------------------------------------------------
extern "C" void kernel_launch(void* const* d_in, const int* in_sizes, int n_in,
                              void* d_out, int out_size, void* d_ws, size_t ws_size,
                              hipStream_t stream)
{
    const float* x  = (const float*)d_in[0];
    const int*   ei = (const int*)d_in[1];
    const float* Wq = (const float*)d_in[2];
    const float* bq = (const float*)d_in[3];
    const float* Wk = (const float*)d_in[4];
    const float* bk = (const float*)d_in[5];
    const float* Wv = (const float*)d_in[6];
    const float* bv = (const float*)d_in[7];
    const float* Ws = (const float*)d_in[8];
    const float* bs = (const float*)d_in[9];
    const float* W1 = (const float*)d_in[10];
    const float* b1 = (const float*)d_in[11];
    const float* W2 = (const float*)d_in[12];
    const float* b2 = (const float*)d_in[13];
    const float* W3 = (const float*)d_in[14];
    const float* b3 = (const float*)d_in[15];
    float* out = (float*)d_out;

    __half* ws = (__half*)d_ws;
    __half* Qh = ws;
    __half* Sh = Qh + (size_t)NN * HD_;
    __half* KV = Sh + (size_t)NN * HD_;
    __half* hbuf = KV + (size_t)NN * 256;
    __half* Wt = hbuf + (size_t)NN * HD_;
    int* deg    = (int*)(Wt + 65536);
    int* offs   = deg + NN;
    int* cursor = offs + NN;
    int* ssrc   = cursor + NN;
    int* bsum   = ssrc + EE;

    (void)hipMemsetAsync(deg, 0, NN * sizeof(int), stream);

    wt_kernel<<<32, 256, 0, stream>>>(Wq, Wk, Wv, Ws, Wt);
    proj_mfma<<<NN / 16, 256, 0, stream>>>(x, Wt, bq, bk, bv, bs, Qh, Sh, KV);
    deg_kernel<<<PART * PBLK, 256, 0, stream>>>(ei, deg);
    scanA_kernel<<<SC_NB, 256, 0, stream>>>(deg, offs, bsum);
    scanB_kernel<<<1, 128, 0, stream>>>(bsum);
    scanC_kernel<<<(NN + 255) / 256, 256, 0, stream>>>(offs, bsum, cursor);
    scatter_kernel<<<PART * PBLK, 256, 0, stream>>>(ei, cursor, ssrc);
    attn_kernel<<<NN / 4, 256, 0, stream>>>(Qh, KV, Sh, offs, deg, ssrc, hbuf);
    mlp_kernel<<<(NN + 255) / 256, 256, 0, stream>>>(hbuf, W1, b1, W2, b2,
                                                     W3, b3, out);
}